// Round 1
// baseline (128.625 us; speedup 1.0000x reference)
//
#include <hip/hip_runtime.h>
#include <stdint.h>

#define N_PTS 256
#define BIG_F 66049.0f   // 257^2 sentinel from reference

// One DPP-min step: x = min(x, dpp_move(x, CTRL)). bound_ctrl=false + old=x
// makes invalid source lanes a no-op (min(x,x)).
template<int CTRL, int ROW_MASK, int BANK_MASK>
__device__ __forceinline__ float dpp_min_f32(float x) {
    int xi = __float_as_int(x);
    int yi = __builtin_amdgcn_update_dpp(xi, xi, CTRL, ROW_MASK, BANK_MASK, false);
    return fminf(x, __int_as_float(yi));
}

// Full wave64 min-reduce, result broadcast to all lanes via readlane(63).
// Canonical rocPRIM sequence: row_shr 1,2,4,8 then row_bcast15 (rows 1,3),
// row_bcast31 (rows 2,3) -> lane 63 holds min of all 64 lanes.
__device__ __forceinline__ float wave_reduce_min_bcast(float x) {
    x = dpp_min_f32<0x111, 0xf, 0xf>(x); // row_shr:1
    x = dpp_min_f32<0x112, 0xf, 0xf>(x); // row_shr:2
    x = dpp_min_f32<0x114, 0xf, 0xf>(x); // row_shr:4
    x = dpp_min_f32<0x118, 0xf, 0xf>(x); // row_shr:8
    x = dpp_min_f32<0x142, 0xa, 0xf>(x); // row_bcast:15
    x = dpp_min_f32<0x143, 0xc, 0xf>(x); // row_bcast:31
    return __int_as_float(__builtin_amdgcn_readlane(__float_as_int(x), 63));
}

// One wave per batch. Lane L owns input candidates k = s*64 + L (s=0..3),
// held in registers. Used candidates are poisoned with NaN x-coordinate:
// their distance becomes NaN, which v_min_f32 (IEEE minNum) ignores.
__global__ __launch_bounds__(256) void greedy_match_kernel(
    const float* __restrict__ input,
    const float* __restrict__ targets,
    float* __restrict__ out,
    int B, float scale)
{
    #pragma clang fp contract(off)
    __shared__ float wsum[4];
    const int lane = threadIdx.x & 63;
    const int wid  = threadIdx.x >> 6;
    const int b    = blockIdx.x * 4 + wid;

    float acc = 0.0f;
    if (b < B) {
        const float2* pin = (const float2*)(input   + (size_t)b * (2 * N_PTS));
        const float2* ptg = (const float2*)(targets + (size_t)b * (2 * N_PTS));

        float px[4], py[4], tx[4], ty[4];
        #pragma unroll
        for (int s = 0; s < 4; ++s) {
            float2 p = pin[s * 64 + lane];
            px[s] = p.x; py[s] = p.y;
            float2 t = ptg[s * 64 + lane];
            tx[s] = t.x; ty[s] = t.y;
        }

        const float NANF = __int_as_float(0x7fc00000);

        #pragma unroll 1
        for (int c = 0; c < 4; ++c) {
            #pragma unroll 1
            for (int j2 = 0; j2 < 64; ++j2) {
                // broadcast target point j = c*64 + j2 from the lane that holds it
                float tjx = __int_as_float(
                    __builtin_amdgcn_readlane(__float_as_int(tx[c]), j2));
                float tjy = __int_as_float(
                    __builtin_amdgcn_readlane(__float_as_int(ty[c]), j2));

                // distances to this lane's 4 candidates (contract OFF: matches
                // the fp32 numpy reference bit-exactly -> identical argmins)
                float dx0 = tjx - px[0], dy0 = tjy - py[0];
                float dx1 = tjx - px[1], dy1 = tjy - py[1];
                float dx2 = tjx - px[2], dy2 = tjy - py[2];
                float dx3 = tjx - px[3], dy3 = tjy - py[3];
                float d0 = dx0 * dx0 + dy0 * dy0;
                float d1 = dx1 * dx1 + dy1 * dy1;
                float d2 = dx2 * dx2 + dy2 * dy2;
                float d3 = dx3 * dx3 + dy3 * dy3;

                // min over unused candidates (NaN = used, skipped by fminf)
                float m = fminf(fminf(d0, d1), fminf(d2, d3));
                m = wave_reduce_min_bcast(m);

                // exact first-min-wins argmin: slot-major ballots, lowest lane
                unsigned long long e0 = __ballot(d0 == m);
                unsigned long long e1 = __ballot(d1 == m);
                unsigned long long e2 = __ballot(d2 == m);
                unsigned long long e3 = __ballot(d3 == m);
                int k;
                if (e0)      k = __ffsll(e0) - 1;
                else if (e1) k = 64  + __ffsll(e1) - 1;
                else if (e2) k = 128 + __ffsll(e2) - 1;
                else         k = 192 + __ffsll(e3) - 1;

                // faithful to reference: se = min(m, BIG); if m >= BIG, k = 0
                if (!(m < BIG_F)) { m = BIG_F; k = 0; }

                acc += m;

                // mark candidate k used: poison its x-coord with NaN
                const int  ks  = k >> 6;
                const bool hit = (lane == (k & 63));
                px[0] = (hit && ks == 0) ? NANF : px[0];
                px[1] = (hit && ks == 1) ? NANF : px[1];
                px[2] = (hit && ks == 2) ? NANF : px[2];
                px[3] = (hit && ks == 3) ? NANF : px[3];
            }
        }
    }

    if (lane == 0) wsum[wid] = acc;
    __syncthreads();
    if (threadIdx.x == 0) {
        float s = (wsum[0] + wsum[1] + wsum[2] + wsum[3]) * scale;
        atomicAdd(out, s);
    }
}

extern "C" void kernel_launch(void* const* d_in, const int* in_sizes, int n_in,
                              void* d_out, int out_size, void* d_ws, size_t ws_size,
                              hipStream_t stream) {
    const float* input   = (const float*)d_in[0];
    const float* targets = (const float*)d_in[1];
    float* out = (float*)d_out;

    const int B = in_sizes[0] / (2 * N_PTS);
    const float scale = 1.0f / ((float)B * (float)(2 * N_PTS));

    // d_out is poisoned 0xAA before every call — zero it (graph-capturable).
    hipMemsetAsync(d_out, 0, sizeof(float) * (size_t)out_size, stream);

    const int blocks = (B + 3) / 4;  // 4 waves (= 4 batches) per 256-thread block
    greedy_match_kernel<<<blocks, 256, 0, stream>>>(input, targets, out, B, scale);
}

// Round 2
// 128.308 us; speedup vs baseline: 1.0025x; 1.0025x over previous
//
#include <hip/hip_runtime.h>
#include <stdint.h>

#define N_PTS 256
#define BIG_F 66049.0f   // 257^2 sentinel from reference

// One DPP-min step: x = min(x, dpp_move(x, CTRL)). bound_ctrl=false + old=x
// makes invalid source lanes a no-op (min(x,x)).
template<int CTRL, int ROW_MASK, int BANK_MASK>
__device__ __forceinline__ float dpp_min_f32(float x) {
    int xi = __float_as_int(x);
    int yi = __builtin_amdgcn_update_dpp(xi, xi, CTRL, ROW_MASK, BANK_MASK, false);
    return fminf(x, __int_as_float(yi));
}

// Full wave64 min-reduce; result returned uniform (readlane 63 -> SGPR).
__device__ __forceinline__ float wave_reduce_min_bcast(float x) {
    x = dpp_min_f32<0x111, 0xf, 0xf>(x); // row_shr:1
    x = dpp_min_f32<0x112, 0xf, 0xf>(x); // row_shr:2
    x = dpp_min_f32<0x114, 0xf, 0xf>(x); // row_shr:4
    x = dpp_min_f32<0x118, 0xf, 0xf>(x); // row_shr:8
    x = dpp_min_f32<0x142, 0xa, 0xf>(x); // row_bcast:15
    x = dpp_min_f32<0x143, 0xc, 0xf>(x); // row_bcast:31
    return __int_as_float(__builtin_amdgcn_readlane(__float_as_int(x), 63));
}

// One 64-target phase. All candidate coords are individually-named registers
// (NO arrays -> no dynamic indexing -> no scratch demotion; R1's VGPR_Count=16
// betrayed the px[]/tx[] arrays living in scratch on the dependency chain).
__device__ __forceinline__ void greedy_phase(
    float txc, float tyc, int lane, float& acc,
    float& px0, float& py0, float& px1, float& py1,
    float& px2, float& py2, float& px3, float& py3)
{
    #pragma clang fp contract(off)
    const float NANF = __int_as_float(0x7fc00000);
    #pragma unroll 1
    for (int j2 = 0; j2 < 64; ++j2) {
        // broadcast target point j = c*64 + j2 from the lane that holds it
        float tjx = __int_as_float(__builtin_amdgcn_readlane(__float_as_int(txc), j2));
        float tjy = __int_as_float(__builtin_amdgcn_readlane(__float_as_int(tyc), j2));

        // distances (contract OFF: bit-exact vs fp32 numpy -> identical argmins)
        float dx0 = tjx - px0, dy0 = tjy - py0;
        float dx1 = tjx - px1, dy1 = tjy - py1;
        float dx2 = tjx - px2, dy2 = tjy - py2;
        float dx3 = tjx - px3, dy3 = tjy - py3;
        float d0 = dx0 * dx0 + dy0 * dy0;
        float d1 = dx1 * dx1 + dy1 * dy1;
        float d2 = dx2 * dx2 + dy2 * dy2;
        float d3 = dx3 * dx3 + dy3 * dy3;

        // min over unused candidates (NaN = used, skipped by v_min_f32 minNum)
        float m = fminf(fminf(d0, d1), fminf(d2, d3));
        m = wave_reduce_min_bcast(m);

        // exact first-min-wins argmin: slot-major ballots, lowest lane.
        // Nested ternaries on uniform values -> s_cselect, no branch bubbles.
        unsigned long long e0 = __ballot(d0 == m);
        unsigned long long e1 = __ballot(d1 == m);
        unsigned long long e2 = __ballot(d2 == m);
        unsigned long long e3 = __ballot(d3 == m);
        int k = e0 ? (__ffsll((long long)e0) - 1)
              : e1 ? (64  + __ffsll((long long)e1) - 1)
              : e2 ? (128 + __ffsll((long long)e2) - 1)
              :      (192 + __ffsll((long long)e3) - 1);

        // faithful to reference: se = min(m, BIG); if m >= BIG, k = 0
        bool ok = (m < BIG_F);
        m = ok ? m : BIG_F;
        k = ok ? k : 0;

        acc += m;

        // mark candidate k used: poison its x-coord with NaN
        const int  ks  = k >> 6;
        const bool hit = (lane == (k & 63));
        px0 = (hit && ks == 0) ? NANF : px0;
        px1 = (hit && ks == 1) ? NANF : px1;
        px2 = (hit && ks == 2) ? NANF : px2;
        px3 = (hit && ks == 3) ? NANF : px3;
    }
}

// One wave per batch. Lane L owns input candidates k = s*64 + L (s=0..3).
__global__ __launch_bounds__(256) void greedy_match_kernel(
    const float* __restrict__ input,
    const float* __restrict__ targets,
    float* __restrict__ out,
    int B, float scale)
{
    __shared__ float wsum[4];
    const int lane = threadIdx.x & 63;
    const int wid  = threadIdx.x >> 6;
    const int b    = blockIdx.x * 4 + wid;

    float acc = 0.0f;
    if (b < B) {
        const float2* pin = (const float2*)(input   + (size_t)b * (2 * N_PTS));
        const float2* ptg = (const float2*)(targets + (size_t)b * (2 * N_PTS));

        float2 p0 = pin[lane],       t0 = ptg[lane];
        float2 p1 = pin[64 + lane],  t1 = ptg[64 + lane];
        float2 p2 = pin[128 + lane], t2 = ptg[128 + lane];
        float2 p3 = pin[192 + lane], t3 = ptg[192 + lane];

        float px0 = p0.x, py0 = p0.y, px1 = p1.x, py1 = p1.y;
        float px2 = p2.x, py2 = p2.y, px3 = p3.x, py3 = p3.y;

        greedy_phase(t0.x, t0.y, lane, acc, px0, py0, px1, py1, px2, py2, px3, py3);
        greedy_phase(t1.x, t1.y, lane, acc, px0, py0, px1, py1, px2, py2, px3, py3);
        greedy_phase(t2.x, t2.y, lane, acc, px0, py0, px1, py1, px2, py2, px3, py3);
        greedy_phase(t3.x, t3.y, lane, acc, px0, py0, px1, py1, px2, py2, px3, py3);
    }

    if (lane == 0) wsum[wid] = acc;
    __syncthreads();
    if (threadIdx.x == 0) {
        float s = (wsum[0] + wsum[1] + wsum[2] + wsum[3]) * scale;
        atomicAdd(out, s);
    }
}

extern "C" void kernel_launch(void* const* d_in, const int* in_sizes, int n_in,
                              void* d_out, int out_size, void* d_ws, size_t ws_size,
                              hipStream_t stream) {
    const float* input   = (const float*)d_in[0];
    const float* targets = (const float*)d_in[1];
    float* out = (float*)d_out;

    const int B = in_sizes[0] / (2 * N_PTS);
    const float scale = 1.0f / ((float)B * (float)(2 * N_PTS));

    // d_out is poisoned 0xAA before every call — zero it (graph-capturable).
    hipMemsetAsync(d_out, 0, sizeof(float) * (size_t)out_size, stream);

    const int blocks = (B + 3) / 4;  // 4 waves (= 4 batches) per 256-thread block
    greedy_match_kernel<<<blocks, 256, 0, stream>>>(input, targets, out, B, scale);
}